// Round 6
// baseline (97.645 us; speedup 1.0000x reference)
//
#include <hip/hip_runtime.h>
#include <climits>

// Problem constants (from the reference):
//   B=4096 samples, E=8 experts, K=4 top-k, P=96, C=32
//   x: [B*K, P, C] f32; gates: [B, E] f32; batch_index, expert_index: [B*K] int
#define BATCH 4096
#define NEXP 8
#define TOPK 4
#define PC 3072   // P*C = 96*32
#define EPSV 2.220446049250313e-16f

typedef float f32x4 __attribute__((ext_vector_type(4)));

// Single fused kernel, one block per output batch row b.
//
// Inverse mapping: (expert_index, batch_index) should be sorted by (e, b)
// (stable argsort-by-expert of a batch-major nonzero listing), so row n for
// pair (e_k, b) is found by lower_bound binary search (14 probes, L2-hot).
// Lanes 0..3 of each wave search the 4 chosen experts in parallel.
//
// DEFENSIVE: each searching lane verifies its hit. If any verification fails
// (wave-uniform ballot), the wave falls back to a strided brute-force scan of
// the full index arrays — correct under ANY ordering. A final clamp makes
// OOB gathers impossible. Accumulation order is ascending expert either way:
// deterministic across calls.
//
// x loads are regular cached loads (partial Infinity-Cache residency across
// graph replays — measured faster than nontemporal in R3->R4). Output stores
// are nontemporal so the 50 MB write stream does not evict x from L3.
__global__ __launch_bounds__(256) void fused_combine_kernel(
        const float* __restrict__ x,
        const float* __restrict__ gates,
        const int* __restrict__ batch_index,
        const int* __restrict__ expert_index,
        float* __restrict__ out,
        int N) {
    const int b    = blockIdx.x;
    const int t    = threadIdx.x;
    const int lane = t & 63;

    // --- extract the 4 chosen experts + gate weights for batch b (uniform,
    //     named scalars only: no runtime-indexed arrays -> no scratch) ---
    const float* grow = gates + b * NEXP;
    int   e0 = 0, e1 = 0, e2 = 0, e3 = 0, cnt = 0;
    float g0 = 0.f, g1 = 0.f, g2 = 0.f, g3 = 0.f;
    #pragma unroll
    for (int q = 0; q < NEXP; ++q) {
        float v = grow[q];
        if (v > 0.0f) {
            if      (cnt == 0) { e0 = q; g0 = v; }
            else if (cnt == 1) { e1 = q; g1 = v; }
            else if (cnt == 2) { e2 = q; g2 = v; }
            else if (cnt == 3) { e3 = q; g3 = v; }
            ++cnt;
        }
    }

    // --- lane-parallel lower_bound for (e_k, b), k = lane in 0..3 ---
    const int   ek = (lane == 0) ? e0 : (lane == 1) ? e1 : (lane == 2) ? e2 : e3;
    const float gk = (lane == 0) ? g0 : (lane == 1) ? g1 : (lane == 2) ? g2 : g3;
    const int key  = ek * BATCH + b;         // lexicographic (e,b) key
    int lo = 0, hi = N;
    for (int it = 0; it < 14; ++it) {        // 2^14 = 16384 = N
        int  mid  = (lo + hi) >> 1;
        int  kmid = expert_index[mid] * BATCH + batch_index[mid];
        bool less = kmid < key;
        lo = less ? mid + 1 : lo;
        hi = less ? hi : mid;
    }

    // --- verify; wave-uniform fallback scan if the sort assumption fails ---
    int  lov = (lo < N) ? lo : (N - 1);
    bool ok  = (lane >= TOPK) || (gk == 0.0f) ||
               (expert_index[lov] == ek && batch_index[lov] == b);
    if (__ballot(ok) != ~0ULL) {
        int f0 = INT_MAX, f1 = INT_MAX, f2 = INT_MAX, f3 = INT_MAX;
        for (int base = lane; base < N; base += 64) {
            if (batch_index[base] == b) {
                int em = expert_index[base];
                if      (em == e0) f0 = base;
                else if (em == e1) f1 = base;
                else if (em == e2) f2 = base;
                else if (em == e3) f3 = base;
            }
        }
        #pragma unroll
        for (int off = 32; off; off >>= 1) {
            f0 = min(f0, __shfl_xor(f0, off, 64));
            f1 = min(f1, __shfl_xor(f1, off, 64));
            f2 = min(f2, __shfl_xor(f2, off, 64));
            f3 = min(f3, __shfl_xor(f3, off, 64));
        }
        lov = (lane == 0) ? f0 : (lane == 1) ? f1 : (lane == 2) ? f2 : f3;
    }
    lov = (lov >= 0 && lov < N) ? lov : 0;   // final OOB guard (g=0 lanes)

    const int n0 = __shfl(lov, 0, 64);
    const int n1 = __shfl(lov, 1, 64);
    const int n2 = __shfl(lov, 2, 64);
    const int n3 = __shfl(lov, 3, 64);

    // --- fused gather + exp + weighted-sum + eps-guard + log ---
    const f32x4* x0 = (const f32x4*)(x + (size_t)n0 * PC) + t;
    const f32x4* x1 = (const f32x4*)(x + (size_t)n1 * PC) + t;
    const f32x4* x2 = (const f32x4*)(x + (size_t)n2 * PC) + t;
    const f32x4* x3 = (const f32x4*)(x + (size_t)n3 * PC) + t;
    f32x4* o = (f32x4*)(out + (size_t)b * PC) + t;

    f32x4 a0[3], a1[3], a2[3], a3[3];        // fully unrolled -> static indices
    #pragma unroll
    for (int j = 0; j < 3; ++j) {
        a0[j] = x0[j * 256];
        a1[j] = x1[j * 256];
        a2[j] = x2[j * 256];
        a3[j] = x3[j * 256];
    }

    #pragma unroll
    for (int j = 0; j < 3; ++j) {
        f32x4 r;
        #pragma unroll
        for (int c = 0; c < 4; ++c) {
            float s = g0 * __expf(a0[j][c]) + g1 * __expf(a1[j][c])
                    + g2 * __expf(a2[j][c]) + g3 * __expf(a3[j][c]);
            r[c] = __logf(s == 0.0f ? EPSV : s);
        }
        __builtin_nontemporal_store(r, o + j * 256);
    }
}

extern "C" void kernel_launch(void* const* d_in, const int* in_sizes, int n_in,
                              void* d_out, int out_size, void* d_ws, size_t ws_size,
                              hipStream_t stream) {
    const float* x            = (const float*)d_in[0];   // [B*K, P, C]
    const float* gates        = (const float*)d_in[1];   // [B, E]
    const int*   batch_index  = (const int*)d_in[2];     // [N]
    const int*   expert_index = (const int*)d_in[3];     // [N]
    float* out = (float*)d_out;
    const int N = in_sizes[2];                           // B*K = 16384
    const int B = in_sizes[1] / NEXP;                    // 4096

    fused_combine_kernel<<<B, 256, 0, stream>>>(
        x, gates, batch_index, expert_index, out, N);
}

// Round 7
// 47.264 us; speedup vs baseline: 2.0660x; 2.0660x over previous
//
#include <hip/hip_runtime.h>
#include <climits>

// Problem constants (from the reference):
//   B=4096 samples, E=8 experts, K=4 top-k, P=96, C=32
//   x: [B*K, P, C] f32; gates: [B, E] f32; batch_index, expert_index: [B*K] int
#define BATCH 4096
#define NEXP 8
#define TOPK 4
#define PC 3072   // P*C = 96*32
#define EPSV 2.220446049250313e-16f

typedef float f32x4 __attribute__((ext_vector_type(4)));

// Single fused kernel, one block per output batch row b.
//
// Inverse mapping: (expert_index, batch_index) is sorted by (e, b) — stable
// argsort-by-expert of a batch-major nonzero listing — so row n for pair
// (e_k, b) is found by lower_bound binary search. N = 2^14, so the search
// needs 15 iterations to fully resolve (14 leaves an interval of size 1 —
// that off-by-one was R5's failure). Lanes 0..3 search in parallel; results
// broadcast via __shfl.
//
// DEFENSIVE: searching lanes verify their hit; on any failure (wave ballot)
// the wave falls back to a strided brute-force scan (correct under any
// ordering). Clamp before gather makes OOB impossible. Accumulation order is
// ascending expert either way: deterministic across calls.
//
// x loads are regular cached loads (measured: L3 retains ~half of x across
// graph replays, FETCH 99 MB < 201 MB). Output stores are nontemporal so the
// 50 MB write stream does not evict x from L3.
__global__ __launch_bounds__(256) void fused_combine_kernel(
        const float* __restrict__ x,
        const float* __restrict__ gates,
        const int* __restrict__ batch_index,
        const int* __restrict__ expert_index,
        float* __restrict__ out,
        int N) {
    const int b    = blockIdx.x;
    const int t    = threadIdx.x;
    const int lane = t & 63;

    // --- extract the 4 chosen experts + gate weights for batch b (uniform,
    //     named scalars only: no runtime-indexed arrays -> no scratch) ---
    const float* grow = gates + b * NEXP;
    int   e0 = 0, e1 = 0, e2 = 0, e3 = 0, cnt = 0;
    float g0 = 0.f, g1 = 0.f, g2 = 0.f, g3 = 0.f;
    #pragma unroll
    for (int q = 0; q < NEXP; ++q) {
        float v = grow[q];
        if (v > 0.0f) {
            if      (cnt == 0) { e0 = q; g0 = v; }
            else if (cnt == 1) { e1 = q; g1 = v; }
            else if (cnt == 2) { e2 = q; g2 = v; }
            else if (cnt == 3) { e3 = q; g3 = v; }
            ++cnt;
        }
    }

    // --- lane-parallel lower_bound for (e_k, b), k = lane in 0..3 ---
    const int   ek = (lane == 0) ? e0 : (lane == 1) ? e1 : (lane == 2) ? e2 : e3;
    const float gk = (lane == 0) ? g0 : (lane == 1) ? g1 : (lane == 2) ? g2 : g3;
    const int key  = ek * BATCH + b;         // lexicographic (e,b) key
    int lo = 0, hi = N;
    for (int it = 0; it < 15; ++it) {        // 15 halvings resolve 2^14 fully
        if (lo < hi) {
            int  mid  = (lo + hi) >> 1;      // mid <= N-1 (key exists in array)
            int  kmid = expert_index[mid] * BATCH + batch_index[mid];
            bool less = kmid < key;
            lo = less ? mid + 1 : lo;
            hi = less ? hi : mid;
        }
    }

    // --- verify; wave-uniform fallback scan if assumption fails ---
    int  lov = (lo < N) ? lo : (N - 1);
    bool ok  = (lane >= TOPK) || (gk == 0.0f) ||
               (expert_index[lov] == ek && batch_index[lov] == b);
    if (__ballot(ok) != ~0ULL) {
        int f0 = INT_MAX, f1 = INT_MAX, f2 = INT_MAX, f3 = INT_MAX;
        for (int base = lane; base < N; base += 64) {
            if (batch_index[base] == b) {
                int em = expert_index[base];
                if      (em == e0) f0 = base;
                else if (em == e1) f1 = base;
                else if (em == e2) f2 = base;
                else if (em == e3) f3 = base;
            }
        }
        #pragma unroll
        for (int off = 32; off; off >>= 1) {
            f0 = min(f0, __shfl_xor(f0, off, 64));
            f1 = min(f1, __shfl_xor(f1, off, 64));
            f2 = min(f2, __shfl_xor(f2, off, 64));
            f3 = min(f3, __shfl_xor(f3, off, 64));
        }
        lov = (lane == 0) ? f0 : (lane == 1) ? f1 : (lane == 2) ? f2 : f3;
    }
    lov = (lov >= 0 && lov < N) ? lov : 0;   // final OOB guard

    const int n0 = __shfl(lov, 0, 64);
    const int n1 = __shfl(lov, 1, 64);
    const int n2 = __shfl(lov, 2, 64);
    const int n3 = __shfl(lov, 3, 64);

    // --- fused gather + exp + weighted-sum + eps-guard + log ---
    const f32x4* x0 = (const f32x4*)(x + (size_t)n0 * PC) + t;
    const f32x4* x1 = (const f32x4*)(x + (size_t)n1 * PC) + t;
    const f32x4* x2 = (const f32x4*)(x + (size_t)n2 * PC) + t;
    const f32x4* x3 = (const f32x4*)(x + (size_t)n3 * PC) + t;
    f32x4* o = (f32x4*)(out + (size_t)b * PC) + t;

    f32x4 a0[3], a1[3], a2[3], a3[3];        // fully unrolled -> static indices
    #pragma unroll
    for (int j = 0; j < 3; ++j) {
        a0[j] = x0[j * 256];
        a1[j] = x1[j * 256];
        a2[j] = x2[j * 256];
        a3[j] = x3[j * 256];
    }

    #pragma unroll
    for (int j = 0; j < 3; ++j) {
        f32x4 r;
        #pragma unroll
        for (int c = 0; c < 4; ++c) {
            float s = g0 * __expf(a0[j][c]) + g1 * __expf(a1[j][c])
                    + g2 * __expf(a2[j][c]) + g3 * __expf(a3[j][c]);
            r[c] = __logf(s == 0.0f ? EPSV : s);
        }
        __builtin_nontemporal_store(r, o + j * 256);
    }
}

extern "C" void kernel_launch(void* const* d_in, const int* in_sizes, int n_in,
                              void* d_out, int out_size, void* d_ws, size_t ws_size,
                              hipStream_t stream) {
    const float* x            = (const float*)d_in[0];   // [B*K, P, C]
    const float* gates        = (const float*)d_in[1];   // [B, E]
    const int*   batch_index  = (const int*)d_in[2];     // [N]
    const int*   expert_index = (const int*)d_in[3];     // [N]
    float* out = (float*)d_out;
    const int N = in_sizes[2];                           // B*K = 16384
    const int B = in_sizes[1] / NEXP;                    // 4096

    fused_combine_kernel<<<B, 256, 0, stream>>>(
        x, gates, batch_index, expert_index, out, N);
}

// Round 8
// 46.117 us; speedup vs baseline: 2.1174x; 1.0249x over previous
//
#include <hip/hip_runtime.h>

// Problem constants (from the reference):
//   B=4096 samples, E=8 experts, K=4 top-k, P=96, C=32
//   x: [B*K, P, C] f32; gates: [B, E] f32; batch_index, expert_index: [B*K] int
#define BATCH 4096
#define NEXP 8
#define TOPK 4
#define PC 3072   // P*C = 96*32
#define EPSV 2.220446049250313e-16f

typedef float f32x4 __attribute__((ext_vector_type(4)));

// Kernel 1: build compacted inverse mapping WITHOUT atomics or zeroing.
// For stitched row n with (b, e): its slot among b's chosen experts is the
// number of chosen experts with index < e (gates row has exactly TOPK
// positives — softmax outputs). Deterministic, bijective onto slots 0..3,
// every slot rewritten every call (poison-safe, no memset needed).
// R7 measured: doing this lookup in-kernel via binary search costs MORE
// (search latency in every block's prologue) than this 2 µs dispatch.
__global__ __launch_bounds__(256) void build_inv_kernel(
        const int* __restrict__ batch_index,
        const int* __restrict__ expert_index,
        const float* __restrict__ gates,
        int* __restrict__ inv,
        float* __restrict__ gval,
        int N) {
    int n = blockIdx.x * blockDim.x + threadIdx.x;
    if (n >= N) return;
    int b = batch_index[n];
    int e = expert_index[n];
    const float* grow = gates + b * NEXP;
    int slot = 0;
    #pragma unroll
    for (int q = 0; q < NEXP - 1; ++q)
        slot += (q < e && grow[q] > 0.0f) ? 1 : 0;
    inv[b * TOPK + slot]  = n;
    gval[b * TOPK + slot] = grow[e];
}

// Kernel 2: fused gather + exp + weighted-sum + eps-guard + log.
// One block (256 threads) per batch row; 3072 floats = 768 float4 = 256 x 3.
// x loads are regular cached loads — measured (R6 FETCH 99 MB < 201 MB):
// Infinity Cache retains ~half of x across graph replays, and cached loads
// beat nontemporal by ~3 µs (R3->R4). Output stores are nontemporal so the
// 50 MB write stream does not evict x from L3.
__global__ __launch_bounds__(256) void combine_kernel(
        const float* __restrict__ x,
        const int* __restrict__ inv,
        const float* __restrict__ gval,
        float* __restrict__ out) {
    const int b = blockIdx.x;
    const int t = threadIdx.x;

    const int   n0 = inv[b * TOPK + 0], n1 = inv[b * TOPK + 1],
                n2 = inv[b * TOPK + 2], n3 = inv[b * TOPK + 3];
    const float g0 = gval[b * TOPK + 0], g1 = gval[b * TOPK + 1],
                g2 = gval[b * TOPK + 2], g3 = gval[b * TOPK + 3];

    const f32x4* x0 = (const f32x4*)(x + (size_t)n0 * PC) + t;
    const f32x4* x1 = (const f32x4*)(x + (size_t)n1 * PC) + t;
    const f32x4* x2 = (const f32x4*)(x + (size_t)n2 * PC) + t;
    const f32x4* x3 = (const f32x4*)(x + (size_t)n3 * PC) + t;
    f32x4* o = (f32x4*)(out + (size_t)b * PC) + t;

    f32x4 a0[3], a1[3], a2[3], a3[3];   // fully unrolled -> static indices
    #pragma unroll
    for (int j = 0; j < 3; ++j) {
        a0[j] = x0[j * 256];
        a1[j] = x1[j * 256];
        a2[j] = x2[j * 256];
        a3[j] = x3[j * 256];
    }

    #pragma unroll
    for (int j = 0; j < 3; ++j) {
        f32x4 r;
        #pragma unroll
        for (int c = 0; c < 4; ++c) {
            float s = g0 * __expf(a0[j][c]) + g1 * __expf(a1[j][c])
                    + g2 * __expf(a2[j][c]) + g3 * __expf(a3[j][c]);
            r[c] = __logf(s == 0.0f ? EPSV : s);
        }
        __builtin_nontemporal_store(r, o + j * 256);
    }
}

extern "C" void kernel_launch(void* const* d_in, const int* in_sizes, int n_in,
                              void* d_out, int out_size, void* d_ws, size_t ws_size,
                              hipStream_t stream) {
    const float* x            = (const float*)d_in[0];   // [B*K, P, C]
    const float* gates        = (const float*)d_in[1];   // [B, E]
    const int*   batch_index  = (const int*)d_in[2];     // [N]
    const int*   expert_index = (const int*)d_in[3];     // [N]
    float* out = (float*)d_out;
    const int N = in_sizes[2];                           // B*K = 16384

    // Workspace layout: inv[B*4] int | gval[B*4] float  (128 KB, fully
    // rewritten by build_inv_kernel every call -> no zeroing needed).
    int*   inv  = (int*)d_ws;
    float* gval = (float*)(inv + BATCH * TOPK);

    build_inv_kernel<<<(N + 255) / 256, 256, 0, stream>>>(
        batch_index, expert_index, gates, inv, gval, N);

    combine_kernel<<<BATCH, 256, 0, stream>>>(x, inv, gval, out);
}